// Round 16
// baseline (121.325 us; speedup 1.0000x reference)
//
#include <hip/hip_runtime.h>
#include <hip/hip_bf16.h>

#define N_ROWS 8192
#define DIM 256
#define NANCH 64
#define NVIEW 128
#define NPART 8     // column partitions (8 anchors = 1024 cols each)

typedef __attribute__((ext_vector_type(8))) short bf16x8;
typedef __attribute__((ext_vector_type(16))) float f32x16;
typedef __attribute__((ext_vector_type(4))) float float4v;
typedef __attribute__((ext_vector_type(4))) unsigned short ushort4v;

__device__ __forceinline__ unsigned short f2bf(float x) {
  union { float f; unsigned int u; } c; c.f = x;
  unsigned int u = c.u;
  unsigned int r = (u + 0x7fffu + ((u >> 16) & 1u)) >> 16;
  return (unsigned short)r;
}

__device__ __forceinline__ float bf2f(unsigned short b) {
  union { unsigned int u; float f; } c; c.u = ((unsigned int)b) << 16;
  return c.f;
}

__device__ __forceinline__ void gload_lds16(const void* g, void* l) {
  __builtin_amdgcn_global_load_lds(
      (const __attribute__((address_space(1))) unsigned int*)g,
      (__attribute__((address_space(3))) unsigned int*)l, 16, 0, 0);
}

// fp32 -> bf16 with 1/sqrt(T) prescale, fused with per-row squared-norm
// (= the Gram diagonal = the row max of the logits). One wave per row.
// (VERBATIM from R8 -- the 44.5 us baseline's producer.)
__global__ void cast_diag_kernel(const float4v* __restrict__ in,
                                 ushort4v* __restrict__ out,
                                 float* __restrict__ diag) {
  const int w = threadIdx.x >> 6;
  const int l = threadIdx.x & 63;
  const int row = blockIdx.x * 4 + w;
  const float s = 3.16227766016838f; // 1/sqrt(0.1)
  float4v v = in[row * 64 + l];
  ushort4v o;
  o.x = f2bf(v.x * s);
  o.y = f2bf(v.y * s);
  o.z = f2bf(v.z * s);
  o.w = f2bf(v.w * s);
  out[row * 64 + l] = o;
  float c0 = bf2f(o.x), c1 = bf2f(o.y), c2 = bf2f(o.z), c3 = bf2f(o.w);
  float ss = c0 * c0 + c1 * c1 + c2 * c2 + c3 * c3;
#pragma unroll
  for (int st = 1; st < 64; st <<= 1) ss += __shfl_xor(ss, st);
  if (l == 0) diag[row] = ss;
}

// -------- Kernel 2: R8's measured-best schedule (44.5 us), VERBATIM except
// ONE change: the ns-only epilogue is replaced by the verified fused
// ns/sd/ep epilogue (kills the separate positives kernel, ~25 us).
// grid = 32 row-pair-blocks x 8 parts (rbp = bx&31, part = bx>>5 -- R8's
// exact mapping), 512 threads = 8 waves (4 row-groups x 2 col-groups),
// 1 block/CU. 16 half-anchor B tiles (64 cols x K=256, 32 KB, k-major
// conflict-free LDS) through a ring-4 staged 3-deep; counted vmcnt
// 12/12/.../8/4/0, raw s_barrier pairs, setprio MFMA cluster (4 chains).
//   NEG anchors -> ns += exp(v - diag)   [underflow-skipped]
//   POS anchors -> sd += (v - diag); ep += exp(v - diag) [diag masked]
__global__ __launch_bounds__(512, 2) void pcl_negsum(
    const unsigned short* __restrict__ Xb, const int* __restrict__ labels,
    const float* __restrict__ diag, float* __restrict__ ns_partial,
    float* __restrict__ sd_partial, float* __restrict__ ep_partial) {
  const int bx = blockIdx.x;
  const int rbp = bx & 31;            // rows rbp*256 .. +255 (2 row-anchors)
  const int part = bx >> 5;           // 0..7 -> col anchors part*8 .. +7
  const int abase = part * 8;
  const int tid = threadIdx.x;
  const int wid = tid >> 6;           // 0..7
  const int lane = tid & 63;
  const int l31 = lane & 31;
  const int khalf = lane >> 5;
  const int rg = wid >> 1;            // row group (64 rows)
  const int cg = wid & 1;             // col group (32 cols)
  const int R0 = rbp * 256;

  __shared__ __align__(16) unsigned short ring[4 * 64 * DIM];  // 4 x 32 KB
  __shared__ float sdiag[256];
  __shared__ float nsacc[256];
  __shared__ float sdacc[256];
  __shared__ float epacc[256];
  __shared__ int slab[NANCH];

  if (tid < NANCH) slab[tid] = labels[tid];
  if (tid < 256) {
    sdiag[tid] = diag[R0 + tid];
    nsacc[tid] = 0.f;
    sdacc[tid] = 0.f;
    epacc[tid] = 0.f;
  }
  __syncthreads();
  const int myLab = slab[rbp * 2 + (rg >> 1)];

  // A fragments: lane holds row R0 + rg*64 + ri*32 + l31, k = ks*16+khalf*8.
  bf16x8 afrag[2][16];
#pragma unroll
  for (int ri = 0; ri < 2; ++ri) {
#pragma unroll
    for (int ks = 0; ks < 16; ++ks) {
      const unsigned short* p =
          Xb + (size_t)(R0 + rg * 64 + ri * 32 + l31) * DIM + ks * 16 + khalf * 8;
      afrag[ri][ks] = *(const bf16x8*)p;
    }
  }
#pragma unroll
  for (int ri = 0; ri < 2; ++ri)
#pragma unroll
    for (int ks = 0; ks < 16; ++ks) asm volatile("" : "+v"(afrag[ri][ks]));

  // Wave-uniform skip threshold: min diag over this wave's 64 rows - 40.
  float thr;
  {
    float d = sdiag[rg * 64 + lane];
#pragma unroll
    for (int st = 1; st < 64; st <<= 1) d = fminf(d, __shfl_xor(d, st));
    thr = d - 40.f;
  }

  char* const L0 = (char*)&ring[0];

  // Stage half-tile H (H=0..15: anchor abase+(H>>1), col-half H&1) into slot
  // H&3. Thread covers chunks g = i*512+tid: k-octet = i*8+wid, col = lane.
#define STAGE(H)                                                                \
  do {                                                                          \
    const unsigned short* _s =                                                  \
        Xb + (size_t)((abase + ((H) >> 1)) * NVIEW + ((H) & 1) * 64 + lane) *   \
                 DIM + wid * 8;                                                 \
    char* _d = L0 + ((H) & 3) * 32768 + wid * 1024;                             \
    gload_lds16(_s, _d);                                                        \
    gload_lds16(_s + 64, _d + 8192);                                            \
    gload_lds16(_s + 128, _d + 16384);                                          \
    gload_lds16(_s + 192, _d + 24576);                                          \
  } while (0)

  STAGE(0);
  STAGE(1);
  STAGE(2);

#define ITER(S, VN)                                                             \
  do {                                                                          \
    if ((S) + 3 < 16) STAGE((S) + 3);                                           \
    asm volatile("s_waitcnt vmcnt(" #VN ")");                                   \
    __builtin_amdgcn_sched_barrier(0);                                          \
    __builtin_amdgcn_s_barrier();                                               \
    __builtin_amdgcn_sched_barrier(0);                                          \
    const char* _sb =                                                           \
        L0 + ((S) & 3) * 32768 + khalf * 1024 + cg * 512 + l31 * 16;            \
    f32x16 a0A = {}, a0B = {}, a1A = {}, a1B = {};                              \
    __builtin_amdgcn_s_setprio(1);                                              \
    _Pragma("unroll") for (int ks = 0; ks < 8; ++ks) {                          \
      bf16x8 b0 = *(const bf16x8*)(_sb + ks * 2048);                            \
      bf16x8 b1 = *(const bf16x8*)(_sb + (ks + 8) * 2048);                      \
      a0A = __builtin_amdgcn_mfma_f32_32x32x16_bf16(afrag[0][ks], b0, a0A, 0, 0, 0); \
      a1A = __builtin_amdgcn_mfma_f32_32x32x16_bf16(afrag[1][ks], b0, a1A, 0, 0, 0); \
      a0B = __builtin_amdgcn_mfma_f32_32x32x16_bf16(afrag[0][ks + 8], b1, a0B, 0, 0, 0); \
      a1B = __builtin_amdgcn_mfma_f32_32x32x16_bf16(afrag[1][ks + 8], b1, a1B, 0, 0, 0); \
    }                                                                           \
    __builtin_amdgcn_s_setprio(0);                                              \
    /* ---- THE ONE CHANGE vs R8: fused ns/sd/ep epilogue ---- */               \
    {                                                                           \
      const bool is_pos = (slab[abase + ((S) >> 1)] == myLab);                  \
      f32x16 c0 = a0A + a0B;                                                    \
      f32x16 c1 = a1A + a1B;                                                    \
      float vmax = fmaxf(c0[0], c1[0]);                                         \
      _Pragma("unroll") for (int r = 1; r < 16; ++r)                            \
          vmax = fmaxf(vmax, fmaxf(c0[r], c1[r]));                              \
      const bool anyhot = __any(vmax > thr);                                    \
      const int gcol = (abase + ((S) >> 1)) * NVIEW + ((S) & 1) * 64 +          \
                       cg * 32 + l31;                                           \
      if (__builtin_expect(is_pos, 0)) {                                        \
        if (!anyhot) {                                                          \
          _Pragma("unroll") for (int ri = 0; ri < 2; ++ri) {                    \
            _Pragma("unroll") for (int r = 0; r < 16; ++r) {                    \
              const int rloc = (r & 3) + 8 * (r >> 2) + 4 * khalf;              \
              const int row = rg * 64 + ri * 32 + rloc;                         \
              float d = (ri ? c1[r] : c0[r]) - sdiag[row];                      \
              _Pragma("unroll") for (int st = 1; st < 32; st <<= 1)             \
                  d += __shfl_xor(d, st);                                       \
              if (l31 == 0) atomicAdd(&sdacc[row], d);                          \
            }                                                                   \
          }                                                                     \
        } else {                                                                \
          _Pragma("unroll") for (int ri = 0; ri < 2; ++ri) {                    \
            _Pragma("unroll") for (int r = 0; r < 16; ++r) {                    \
              const int rloc = (r & 3) + 8 * (r >> 2) + 4 * khalf;              \
              const int row = rg * 64 + ri * 32 + rloc;                         \
              const bool isdiag = (R0 + row) == gcol;                           \
              float v = (ri ? c1[r] : c0[r]);                                   \
              float d = v - sdiag[row];                                         \
              float sd_e = isdiag ? 0.f : d;                                    \
              float e = (!isdiag && d > -40.f) ? __expf(d) : 0.f;               \
              _Pragma("unroll") for (int st = 1; st < 32; st <<= 1) {           \
                sd_e += __shfl_xor(sd_e, st);                                   \
                e += __shfl_xor(e, st);                                         \
              }                                                                 \
              if (l31 == 0) {                                                   \
                atomicAdd(&sdacc[row], sd_e);                                   \
                if (e != 0.f) atomicAdd(&epacc[row], e);                        \
              }                                                                 \
            }                                                                   \
          }                                                                     \
        }                                                                       \
      } else if (__builtin_expect(anyhot, 0)) {                                 \
        _Pragma("unroll") for (int ri = 0; ri < 2; ++ri) {                      \
          _Pragma("unroll") for (int r = 0; r < 16; ++r) {                      \
            const int rloc = (r & 3) + 8 * (r >> 2) + 4 * khalf;                \
            const int row = rg * 64 + ri * 32 + rloc;                           \
            float d = (ri ? c1[r] : c0[r]) - sdiag[row];                        \
            float e = (d > -40.f) ? __expf(d) : 0.f;                            \
            _Pragma("unroll") for (int st = 1; st < 32; st <<= 1)               \
                e += __shfl_xor(e, st);                                         \
            if (l31 == 0) atomicAdd(&nsacc[row], e);                            \
          }                                                                     \
        }                                                                       \
      }                                                                         \
    }                                                                           \
    __builtin_amdgcn_s_barrier();                                               \
  } while (0)

  ITER(0, 12);  ITER(1, 12);  ITER(2, 12);  ITER(3, 12);
  ITER(4, 12);  ITER(5, 12);  ITER(6, 12);  ITER(7, 12);
  ITER(8, 12);  ITER(9, 12);  ITER(10, 12); ITER(11, 12);
  ITER(12, 12); ITER(13, 8);  ITER(14, 4);  ITER(15, 0);

#undef ITER
#undef STAGE

  __syncthreads();
  if (tid < 256) {
    ns_partial[part * N_ROWS + R0 + tid] = nsacc[tid];
    sd_partial[part * N_ROWS + R0 + tid] = sdacc[tid];
    ep_partial[part * N_ROWS + R0 + tid] = epacc[tid];
  }
}

// -------- Kernel 3: per-row combine. 32 blocks x 256 threads, 1 row/thread.
// mean_log_prob_pos = (SD - npos*log(NS+eps) - EP/(NS+eps)) / npos
__global__ void pcl_combine(const int* __restrict__ labels,
                            const float* __restrict__ ns_partial,
                            const float* __restrict__ sd_partial,
                            const float* __restrict__ ep_partial,
                            float* __restrict__ partials) {
  const int tid = threadIdx.x;
  const int row = blockIdx.x * 256 + tid;
  __shared__ int slab[NANCH];
  __shared__ float sred[256];
  if (tid < NANCH) slab[tid] = labels[tid];
  __syncthreads();

  const int lab = slab[row >> 7];
  int cnt = 0;
#pragma unroll
  for (int b = 0; b < NANCH; ++b) cnt += (slab[b] == lab) ? 1 : 0;

  float NS = 0.f, SD = 0.f, EP = 0.f;
#pragma unroll
  for (int p = 0; p < NPART; ++p) {
    NS += ns_partial[p * N_ROWS + row];
    SD += sd_partial[p * N_ROWS + row];
    EP += ep_partial[p * N_ROWS + row];
  }
  const float npos = (float)(cnt * NVIEW - 1);
  const float nse = NS + 1e-10f;
  const float mlpp = (SD - npos * __logf(nse) - EP / nse) / npos;
  sred[tid] = mlpp;
  __syncthreads();
  for (int st = 128; st > 0; st >>= 1) {
    if (tid < st) sred[tid] += sred[tid + st];
    __syncthreads();
  }
  if (tid == 0) partials[blockIdx.x] = sred[0];
}

__global__ void final_reduce(const float* __restrict__ partials, float* __restrict__ out) {
  __shared__ float s[32];
  int t = threadIdx.x;
  if (t < 32) s[t] = partials[t];
  __syncthreads();
  if (t == 0) {
    float sum = 0.f;
    for (int r = 0; r < 32; ++r) sum += s[r];
    out[0] = -(0.1f / 0.07f) * sum / (float)N_ROWS;
  }
}

extern "C" void kernel_launch(void* const* d_in, const int* in_sizes, int n_in,
                              void* d_out, int out_size, void* d_ws, size_t ws_size,
                              hipStream_t stream) {
  const float* feats = (const float*)d_in[0];
  const int* labels = (const int*)d_in[1];
  float* out = (float*)d_out;

  char* base = (char*)d_ws;
  unsigned short* Xb = (unsigned short*)d_ws;                      // 4 MB
  size_t off = (size_t)N_ROWS * DIM * 2;
  float* diag = (float*)(base + off);       off += N_ROWS * 4;     // 32 KB
  float* ns_partial = (float*)(base + off); off += (size_t)NPART * N_ROWS * 4;
  float* sd_partial = (float*)(base + off); off += (size_t)NPART * N_ROWS * 4;
  float* ep_partial = (float*)(base + off); off += (size_t)NPART * N_ROWS * 4;
  float* partials = (float*)(base + off);

  cast_diag_kernel<<<N_ROWS / 4, 256, 0, stream>>>((const float4v*)feats,
                                                   (ushort4v*)Xb, diag);
  pcl_negsum<<<32 * NPART, 512, 0, stream>>>(Xb, labels, diag, ns_partial,
                                             sd_partial, ep_partial);
  pcl_combine<<<N_ROWS / 256, 256, 0, stream>>>(labels, ns_partial, sd_partial,
                                                ep_partial, partials);
  final_reduce<<<1, 64, 0, stream>>>(partials, out);
}